// Round 1
// 853.061 us; speedup vs baseline: 1.0173x; 1.0173x over previous
//
#include <hip/hip_runtime.h>
#include <cstdint>

typedef unsigned short u16;
typedef unsigned int u32;
typedef __bf16 bf8 __attribute__((ext_vector_type(8)));
typedef float f4 __attribute__((ext_vector_type(4)));

// ---------- bf16 helpers (bit-level, RNE) ----------
__device__ __forceinline__ float bfl(u32 x) { return __builtin_bit_cast(float, x << 16); }
__device__ __forceinline__ float bfh(u32 x) { return __builtin_bit_cast(float, x & 0xffff0000u); }
__device__ __forceinline__ u16 f2b(float f) {
    u32 u = __builtin_bit_cast(u32, f);
    u += 0x7fffu + ((u >> 16) & 1u);
    return (u16)(u >> 16);
}

// fast GELU: tanh approximation in sigmoid form (max err ~3e-3 << 0.135 thr)
__device__ __forceinline__ float fgelu(float u) {
    float t = u * (1.5957691216057308f + 0.07135481627859035f * u * u);
    return u / (1.f + __expf(-t));
}

// ---------- async global->LDS, 16B per lane ----------
__device__ __forceinline__ void async16(const u16* g, u16* l) {
    auto gp = (const __attribute__((address_space(1))) u32*)(uintptr_t)g;
    auto lp = (__attribute__((address_space(3))) u32*)(uintptr_t)l;
    __builtin_amdgcn_global_load_lds(gp, lp, 16, 0, 0);
}

// ---------- problem constants ----------
#define CH 256
#define HH 56
#define HWSZ 3136          // 56*56
#define TOK 100352         // 32*3136 = 784*128
#define QKVW 768

// =====================================================================
// GEMM core: 128x128 tile, BK=64, 256 threads (4 waves 2x2 of 64x64),
// mfma_f32_16x16x32_bf16, acc[4][4].
// R6: double-buffered LDS (2x32KB) + prefetch-next-before-compute
// (T3-minimum 2-phase): per K-step cost goes from load+compute to
// max(load, compute); single barrier per step, whose implicit vmcnt(0)
// drain lands after the MFMA cluster instead of before it.
// LDS per buf 16KB chunk-planar: (k-chunk q in [0,8), row, j) at
// [(q*128+row)*8+j] = lane-contiguous order global_load_lds writes.
// XCD swizzle: xcd = id&7 owns y-band [xcd*98, xcd*98+98), x fastest ->
// N-tiles of a row-tile co-resident on one XCD sharing A in its L2.
// =====================================================================
template <int K, int XT>
__device__ __forceinline__ void gemm_core(const u16* __restrict__ A, const u16* __restrict__ Bt,
                                          u16* sA, u16* sB, f4 (&acc)[4][4],
                                          int& yo, int& xo) {
    const int id = blockIdx.x;
    const int xcd = id & 7, slot = id >> 3;
    const int y = xcd * 98 + slot / XT;
    const int x = slot % XT;
    yo = y; xo = x;
    const int tid = threadIdx.x;
    const int lane = tid & 63, wv = tid >> 6;
    const int wy = wv >> 1, wx = wv & 1;
    const int qd = lane >> 4, lr = lane & 15;
    const long row0 = (long)y * 128;
    const long col0 = (long)x * 128;

#pragma unroll
    for (int a = 0; a < 4; ++a)
#pragma unroll
        for (int b = 0; b < 4; ++b)
#pragma unroll
            for (int r = 0; r < 4; ++r) acc[a][b][r] = 0.f;

    // 128 rows x 64 k = 1024 16B-chunks per matrix -> 4 per thread
    const u16* ga[4];
    const u16* gb[4];
    int lo[4];
#pragma unroll
    for (int s = 0; s < 4; ++s) {
        int li = tid + 256 * s;
        ga[s] = A + (row0 + (li & 127)) * K + (li >> 7) * 8;
        gb[s] = Bt + (col0 + (li & 127)) * K + (li >> 7) * 8;
        lo[s] = li * 8;
    }

    // prologue: stage tile 0 into buffer 0
#pragma unroll
    for (int s = 0; s < 4; ++s) {
        async16(ga[s], sA + lo[s]);
        async16(gb[s], sB + lo[s]);
        ga[s] += 64; gb[s] += 64;
    }
    __syncthreads();  // drains vmcnt -> buf0 valid

    const int NT = K / 64;
    int cur = 0;
    for (int t = 0; t < NT; ++t) {
        // prefetch next tile into the other buffer (overlaps with compute)
        if (t + 1 < NT) {
            const int nb = (cur ^ 1) * 8192;
#pragma unroll
            for (int s = 0; s < 4; ++s) {
                async16(ga[s], sA + nb + lo[s]);
                async16(gb[s], sB + nb + lo[s]);
                ga[s] += 64; gb[s] += 64;
            }
        }
        const u16* cA = sA + cur * 8192;
        const u16* cB = sB + cur * 8192;
#pragma unroll
        for (int kk = 0; kk < 2; ++kk) {
            const int ao = ((kk * 4 + qd) * 128 + wy * 64 + lr) * 8;
            const int bo = ((kk * 4 + qd) * 128 + wx * 64 + lr) * 8;
            bf8 av[4], bv[4];
#pragma unroll
            for (int mt = 0; mt < 4; ++mt) av[mt] = *(const bf8*)(cA + ao + mt * 128);
#pragma unroll
            for (int nt = 0; nt < 4; ++nt) bv[nt] = *(const bf8*)(cB + bo + nt * 128);
            __builtin_amdgcn_s_setprio(1);
#pragma unroll
            for (int mt = 0; mt < 4; ++mt)
#pragma unroll
                for (int nt = 0; nt < 4; ++nt)
                    acc[mt][nt] = __builtin_amdgcn_mfma_f32_16x16x32_bf16(av[mt], bv[nt], acc[mt][nt], 0, 0, 0);
            __builtin_amdgcn_s_setprio(0);
        }
        if (t + 1 < NT) {
            __syncthreads();  // drains prefetch vmcnt; protects WAR on buf flip
            cur ^= 1;
        }
    }
}

// windowed row -> token-major index (undo window partition + roll(+3))
__device__ __forceinline__ long wtok(int rw) {
    int win = rw / 49, n = rw - win * 49;
    int b = win >> 6, wrc = win & 63;
    int hp = (wrc >> 3) * 7 + n / 7;
    int wp = (wrc & 7) * 7 + n % 7;
    int h = hp + 3; if (h >= HH) h -= HH;
    int w = wp + 3; if (w >= HH) w -= HH;
    return (long)b * HWSZ + h * HH + w;
}

// ---------- GEMM 1: QKV = Yw @ qkv_w + qkv_b  (bf16 out, windowed rows) ----------
__global__ __launch_bounds__(256) void gemm_qkv_kernel(const u16* __restrict__ A, const u16* __restrict__ Bt,
                                                       const float* __restrict__ bias, u16* __restrict__ C) {
    __shared__ u16 sA[2 * 8192], sB[2 * 8192];
    f4 acc[4][4];
    int y, x;
    gemm_core<256, 6>(A, Bt, sA, sB, acc, y, x);
    const int tid = threadIdx.x, lane = tid & 63, wv = tid >> 6;
    const int wy = wv >> 1, wx = wv & 1, qd = lane >> 4, lr = lane & 15;
    const long row0 = (long)y * 128 + wy * 64 + qd * 4;
    const int col0 = x * 128 + wx * 64 + lr;
#pragma unroll
    for (int mt = 0; mt < 4; ++mt) {
        long rb = row0 + mt * 16;
#pragma unroll
        for (int nt = 0; nt < 4; ++nt) {
            int c = col0 + nt * 16;
            float bv = bias[c];
#pragma unroll
            for (int r = 0; r < 4; ++r) C[(rb + r) * QKVW + c] = f2b(acc[mt][nt][r] + bv);
        }
    }
}

// ---------- GEMM 2: x1 += unwindow(Ow @ proj_w + proj_b) ----------
__global__ __launch_bounds__(256) void gemm_proj_kernel(const u16* __restrict__ A, const u16* __restrict__ Bt,
                                                        const float* __restrict__ bias, float* __restrict__ x1) {
    __shared__ u16 sA[2 * 8192], sB[2 * 8192];
    f4 acc[4][4];
    int y, x;
    gemm_core<256, 2>(A, Bt, sA, sB, acc, y, x);
    const int tid = threadIdx.x, lane = tid & 63, wv = tid >> 6;
    const int wy = wv >> 1, wx = wv & 1, qd = lane >> 4, lr = lane & 15;
    const int row0 = y * 128 + wy * 64 + qd * 4;
    const int col0 = x * 128 + wx * 64 + lr;
#pragma unroll
    for (int mt = 0; mt < 4; ++mt) {
        long tk[4];
#pragma unroll
        for (int r = 0; r < 4; ++r) tk[r] = wtok(row0 + mt * 16 + r);
#pragma unroll
        for (int nt = 0; nt < 4; ++nt) {
            int c = col0 + nt * 16;
            float bv = bias[c];
#pragma unroll
            for (int r = 0; r < 4; ++r) x1[tk[r] * CH + c] += acc[mt][nt][r] + bv;
        }
    }
}

// ---------- GEMM 3: Hid = gelu(L2 @ w1 + b1) (bf16 out) ----------
__global__ __launch_bounds__(256) void gemm_mlp1_kernel(const u16* __restrict__ A, const u16* __restrict__ Bt,
                                                        const float* __restrict__ bias, u16* __restrict__ C) {
    __shared__ u16 sA[2 * 8192], sB[2 * 8192];
    f4 acc[4][4];
    int y, x;
    gemm_core<256, 8>(A, Bt, sA, sB, acc, y, x);
    const int tid = threadIdx.x, lane = tid & 63, wv = tid >> 6;
    const int wy = wv >> 1, wx = wv & 1, qd = lane >> 4, lr = lane & 15;
    const long row0 = (long)y * 128 + wy * 64 + qd * 4;
    const int col0 = x * 128 + wx * 64 + lr;
#pragma unroll
    for (int mt = 0; mt < 4; ++mt) {
        long rb = row0 + mt * 16;
#pragma unroll
        for (int nt = 0; nt < 4; ++nt) {
            int c = col0 + nt * 16;
            float bv = bias[c];
#pragma unroll
            for (int r = 0; r < 4; ++r)
                C[(rb + r) * 1024 + c] = f2b(fgelu(acc[mt][nt][r] + bv));
        }
    }
}

// ---------- GEMM 4: out(B,C,H,W) = transpose(x1 + Hid @ w2 + b2) ----------
__global__ __launch_bounds__(256) void gemm_mlp2_kernel(const u16* __restrict__ A, const u16* __restrict__ Bt,
                                                        const float* __restrict__ bias, const float* __restrict__ x1,
                                                        float* __restrict__ out) {
    __shared__ u16 sA[2 * 8192], sB[2 * 8192];
    f4 acc[4][4];
    int y, x;
    gemm_core<1024, 2>(A, Bt, sA, sB, acc, y, x);
    const int tid = threadIdx.x, lane = tid & 63, wv = tid >> 6;
    const int wy = wv >> 1, wx = wv & 1, qd = lane >> 4, lr = lane & 15;
    const long row0 = (long)y * 128 + wy * 64 + qd * 4;
    const int col0 = x * 128 + wx * 64 + lr;
#pragma unroll
    for (int mt = 0; mt < 4; ++mt) {
        long r0 = row0 + mt * 16;                 // token index, multiple of 4
        long b = r0 / HWSZ, hw = r0 - b * HWSZ;   // 3136%4==0 -> quad never crosses b
#pragma unroll
        for (int nt = 0; nt < 4; ++nt) {
            int c = col0 + nt * 16;
            float bv = bias[c];
            f4 o;
#pragma unroll
            for (int r = 0; r < 4; ++r) o[r] = acc[mt][nt][r] + bv + x1[(r0 + r) * CH + c];
            *(f4*)(out + (b * CH + c) * HWSZ + hw) = o;
        }
    }
}

// ---------- LN1 + roll(-3) + window partition; also writes f32 shortcut into x1 ----------
__global__ __launch_bounds__(256) void ln1_kernel(const float* __restrict__ x, const float* __restrict__ g,
                                                  const float* __restrict__ be, float* __restrict__ x1,
                                                  u16* __restrict__ Yw) {
    __shared__ float tile[32 * 257];
    __shared__ float red0[256], red1[256];
    __shared__ float smu[32], srs[32];
    const int tid = threadIdx.x;
    const int blk = blockIdx.x;
    const int b = blk / 98, hw0 = (blk - b * 98) * 32;
    const int ty = tid >> 5, tx = tid & 31;
    const float* xb = x + (size_t)b * (CH * HWSZ) + hw0 + tx;
    float s = 0.f, q = 0.f;
#pragma unroll
    for (int ci = 0; ci < 32; ++ci) {
        int c = ty + ci * 8;
        float v = xb[c * HWSZ];
        tile[tx * 257 + c] = v;
        s += v; q += v * v;
    }
    red0[tid] = s;
    red1[tid] = q;
    __syncthreads();
    if (tid < 32) {
        float ss = 0.f, qq = 0.f;
#pragma unroll
        for (int j = 0; j < 8; ++j) { ss += red0[j * 32 + tid]; qq += red1[j * 32 + tid]; }
        float mu = ss * (1.f / 256.f);
        float var = qq * (1.f / 256.f) - mu * mu;
        smu[tid] = mu;
        srs[tid] = rsqrtf(var + 1e-5f);
    }
    __syncthreads();
    const int cl = tid & 31, tg = tid >> 5;
#pragma unroll
    for (int it = 0; it < 4; ++it) {
        int tok = tg + it * 8;
        float mu = smu[tok], rs = srs[tok];
        int hw = hw0 + tok;
        int h = hw / HH, w = hw - h * HH;
        int hp = h - 3; if (hp < 0) hp += HH;
        int wp = w - 3; if (wp < 0) wp += HH;
        long t = (long)b * HWSZ + hw;
        long rowY = (((long)(b * 64 + (hp / 7) * 8 + wp / 7)) * 49 + (hp % 7) * 7 + (wp % 7)) * CH;
        float* xr = x1 + t * CH;
#pragma unroll
        for (int j = 0; j < 8; ++j) {
            int c = j * 32 + cl;
            float v = tile[tok * 257 + c];
            xr[c] = v;  // shortcut (pre-LN), token-major
            Yw[rowY + c] = f2b((v - mu) * rs * g[c] + be[c]);
        }
    }
}

// ---------- LN2: x1 (f32 token-major) -> bf16 ----------
__global__ __launch_bounds__(256) void ln2_kernel(const float* __restrict__ x1, const float* __restrict__ g,
                                                  const float* __restrict__ be, u16* __restrict__ L2) {
    const long t = (long)blockIdx.x * 4 + (threadIdx.x >> 6);
    const int lane = threadIdx.x & 63;
    const float4 v = *(const float4*)(x1 + t * CH + lane * 4);
    float s = v.x + v.y + v.z + v.w;
    float q = v.x * v.x + v.y * v.y + v.z * v.z + v.w * v.w;
#pragma unroll
    for (int m = 1; m < 64; m <<= 1) {
        s += __shfl_xor(s, m, 64);
        q += __shfl_xor(q, m, 64);
    }
    float mu = s * (1.f / 256.f);
    float rs = rsqrtf(q * (1.f / 256.f) - mu * mu + 1e-5f);
    const float4 gg = *(const float4*)(g + lane * 4);
    const float4 bb = *(const float4*)(be + lane * 4);
    ushort4 o;
    o.x = f2b((v.x - mu) * rs * gg.x + bb.x);
    o.y = f2b((v.y - mu) * rs * gg.y + bb.y);
    o.z = f2b((v.z - mu) * rs * gg.z + bb.z);
    o.w = f2b((v.w - mu) * rs * gg.w + bb.w);
    *(ushort4*)(L2 + t * CH + lane * 4) = o;
}

// ---------- MFMA attention: 1 wave per (window, head), 49 tokens padded to 64 ----------
__global__ __launch_bounds__(256) void attn_kernel(const u16* __restrict__ QKV, u16* __restrict__ Ow) {
    __shared__ __align__(16) u16 pbuf[4][64 * 72];  // per-wave P slab (9216 B)
    const int tid = threadIdx.x;
    const int lane = tid & 63, wv = tid >> 6;
    const int pair = blockIdx.x * 4 + wv;
    const int win = pair >> 3, hd = pair & 7;
    const int lr = lane & 15, qd = lane >> 4;
    const u16* base = QKV + (size_t)win * (49 * QKVW) + hd * 32;

    // --- S = Q K^T ---
    bf8 aq[4], bk[4];
#pragma unroll
    for (int t = 0; t < 4; ++t) {
        int rq = t * 16 + lr; if (rq > 48) rq = 48;           // clamp pad rows
        const u16* rp = base + (size_t)rq * QKVW + qd * 8;
        aq[t] = *(const bf8*)(rp);                            // Q
        bk[t] = *(const bf8*)(rp + 256);                      // K
    }
    f4 s[4][4];
#pragma unroll
    for (int mt = 0; mt < 4; ++mt)
#pragma unroll
        for (int nt = 0; nt < 4; ++nt) {
#pragma unroll
            for (int r = 0; r < 4; ++r) s[mt][nt][r] = 0.f;
            s[mt][nt] = __builtin_amdgcn_mfma_f32_16x16x32_bf16(aq[mt], bk[nt], s[mt][nt], 0, 0, 0);
        }

    // --- softmax over cols (0..48 valid), P -> LDS ---
    const float SC = 0.17677669529663687f;  // 1/sqrt(32)
    float inv[4][4];
    u16* slab = pbuf[wv];
#pragma unroll
    for (int mt = 0; mt < 4; ++mt)
#pragma unroll
        for (int r = 0; r < 4; ++r) {
            float v0 = s[mt][0][r] * SC;
            float v1 = s[mt][1][r] * SC;
            float v2 = s[mt][2][r] * SC;
            float v3 = (lr == 0) ? s[mt][3][r] * SC : -3e38f;  // col 48+lr >= 49 masked
            float mx = fmaxf(fmaxf(v0, v1), fmaxf(v2, v3));
#pragma unroll
            for (int m = 1; m < 16; m <<= 1) mx = fmaxf(mx, __shfl_xor(mx, m, 64));
            v0 = __expf(v0 - mx); v1 = __expf(v1 - mx);
            v2 = __expf(v2 - mx); v3 = __expf(v3 - mx);
            float den = (v0 + v1) + (v2 + v3);
#pragma unroll
            for (int m = 1; m < 16; m <<= 1) den += __shfl_xor(den, m, 64);
            inv[mt][r] = 1.f / den;
            u16* pr = slab + (mt * 16 + qd * 4 + r) * 72 + lr;
            pr[0] = f2b(v0); pr[16] = f2b(v1); pr[32] = f2b(v2); pr[48] = f2b(v3);
        }
    // NOTE: no __syncthreads() here — each wave reads only its own pbuf[wv]
    // slab; the compiler's lgkmcnt insertion orders ds_write -> ds_read
    // within the wave. The barrier was forcing 4 independent waves into
    // lockstep for no correctness reason.

    // --- O = P V ---
    f4 o[4][2];
#pragma unroll
    for (int mt = 0; mt < 4; ++mt)
#pragma unroll
        for (int nt = 0; nt < 2; ++nt)
#pragma unroll
            for (int r = 0; r < 4; ++r) o[mt][nt][r] = 0.f;
#pragma unroll
    for (int kt = 0; kt < 2; ++kt) {
        bf8 ap[4];
#pragma unroll
        for (int mt = 0; mt < 4; ++mt)
            ap[mt] = *(const bf8*)(slab + (mt * 16 + lr) * 72 + kt * 32 + qd * 8);
        bf8 bvv[2];
#pragma unroll
        for (int nt = 0; nt < 2; ++nt)
#pragma unroll
            for (int j = 0; j < 8; ++j) {
                int row = kt * 32 + qd * 8 + j; if (row > 48) row = 48;  // P=0 there anyway
                bvv[nt][j] = __builtin_bit_cast(__bf16, base[(size_t)row * QKVW + 512 + nt * 16 + lr]);
            }
#pragma unroll
        for (int mt = 0; mt < 4; ++mt)
#pragma unroll
            for (int nt = 0; nt < 2; ++nt)
                o[mt][nt] = __builtin_amdgcn_mfma_f32_16x16x32_bf16(ap[mt], bvv[nt], o[mt][nt], 0, 0, 0);
    }

    // --- store O (rows < 49) ---
#pragma unroll
    for (int mt = 0; mt < 4; ++mt)
#pragma unroll
        for (int r = 0; r < 4; ++r) {
            int row = mt * 16 + qd * 4 + r;
            if (row < 49) {
                u16* orow = Ow + ((size_t)win * 49 + row) * CH + hd * 32 + lr;
                orow[0]  = f2b(o[mt][0][r] * inv[mt][r]);
                orow[16] = f2b(o[mt][1][r] * inv[mt][r]);
            }
        }
}

// ---------- weight transpose: src[K][N] f32 -> dst[N][K] bf16, LDS 32x33 tile ----------
__global__ __launch_bounds__(256) void transp_kernel(const float* __restrict__ src, u16* __restrict__ dst,
                                                     int K, int N) {
    __shared__ float t[32][33];
    const int n0 = blockIdx.x * 32, k0 = blockIdx.y * 32;
    const int tx = threadIdx.x & 31, ty = threadIdx.x >> 5;
#pragma unroll
    for (int j = 0; j < 32; j += 8)
        t[ty + j][tx] = src[(size_t)(k0 + ty + j) * N + n0 + tx];
    __syncthreads();
#pragma unroll
    for (int j = 0; j < 32; j += 8)
        dst[(size_t)(n0 + ty + j) * K + k0 + tx] = f2b(t[tx][ty + j]);
}

extern "C" void kernel_launch(void* const* d_in, const int* in_sizes, int n_in,
                              void* d_out, int out_size, void* d_ws, size_t ws_size,
                              hipStream_t stream) {
    (void)in_sizes; (void)n_in; (void)out_size; (void)ws_size;
    const float* x      = (const float*)d_in[0];
    const float* n1_g   = (const float*)d_in[1];
    const float* n1_b   = (const float*)d_in[2];
    const float* qkv_w  = (const float*)d_in[3];
    const float* qkv_b  = (const float*)d_in[4];
    const float* proj_w = (const float*)d_in[5];
    const float* proj_b = (const float*)d_in[6];
    const float* n2_g   = (const float*)d_in[7];
    const float* n2_b   = (const float*)d_in[8];
    const float* mlp_w1 = (const float*)d_in[9];
    const float* mlp_b1 = (const float*)d_in[10];
    const float* mlp_w2 = (const float*)d_in[11];
    const float* mlp_b2 = (const float*)d_in[12];
    float* out = (float*)d_out;

    // ws carve. bufA multiplexes Yw -> Ow -> LN2out; bufB multiplexes QKV -> Hid.
    uint8_t* w = (uint8_t*)d_ws;
    u16* bufA = (u16*)(w);                                     //  51,380,224
    u16* bufB = (u16*)(w + 51380224);                          // 205,520,896
    float* x1 = (float*)(w + 51380224 + 205520896);            // 102,760,448
    u16* wq  = (u16*)(w + 359661568);
    u16* wp  = (u16*)(w + 360054784);
    u16* w1t = (u16*)(w + 360185856);
    u16* w2t = (u16*)(w + 360710144);

    transp_kernel<<<dim3(24, 8),  256, 0, stream>>>(qkv_w,  wq,  256, 768);
    transp_kernel<<<dim3(8, 8),   256, 0, stream>>>(proj_w, wp,  256, 256);
    transp_kernel<<<dim3(32, 8),  256, 0, stream>>>(mlp_w1, w1t, 256, 1024);
    transp_kernel<<<dim3(8, 32),  256, 0, stream>>>(mlp_w2, w2t, 1024, 256);
    ln1_kernel<<<3136, 256, 0, stream>>>(x, n1_g, n1_b, x1, bufA);
    gemm_qkv_kernel<<<6 * 784, 256, 0, stream>>>(bufA, wq, qkv_b, bufB);
    attn_kernel<<<4096, 256, 0, stream>>>(bufB, bufA);
    gemm_proj_kernel<<<2 * 784, 256, 0, stream>>>(bufA, wp, proj_b, x1);
    ln2_kernel<<<25088, 256, 0, stream>>>(x1, n2_g, n2_b, bufA);
    gemm_mlp1_kernel<<<8 * 784, 256, 0, stream>>>(bufA, w1t, mlp_b1, bufB);
    gemm_mlp2_kernel<<<2 * 784, 256, 0, stream>>>(bufB, w2t, mlp_b2, x1, out);
}

// Round 4
// 842.129 us; speedup vs baseline: 1.0305x; 1.0130x over previous
//
#include <hip/hip_runtime.h>
#include <cstdint>

typedef unsigned short u16;
typedef unsigned int u32;
typedef __bf16 bf8 __attribute__((ext_vector_type(8)));
typedef float f4 __attribute__((ext_vector_type(4)));

// ---------- bf16 helpers (bit-level, RNE) ----------
__device__ __forceinline__ u16 f2b(float f) {
    u32 u = __builtin_bit_cast(u32, f);
    u += 0x7fffu + ((u >> 16) & 1u);
    return (u16)(u >> 16);
}

// fast GELU: tanh approximation in sigmoid form (max err ~3e-3 << 0.135 thr)
__device__ __forceinline__ float fgelu(float u) {
    float t = u * (1.5957691216057308f + 0.07135481627859035f * u * u);
    return u / (1.f + __expf(-t));
}

// ---------- async global->LDS, 16B per lane ----------
__device__ __forceinline__ void async16(const u16* g, u16* l) {
    auto gp = (const __attribute__((address_space(1))) u32*)(uintptr_t)g;
    auto lp = (__attribute__((address_space(3))) u32*)(uintptr_t)l;
    __builtin_amdgcn_global_load_lds(gp, lp, 16, 0, 0);
}

// ---------- problem constants ----------
#define CH 256
#define HH 56
#define HWSZ 3136          // 56*56
#define TOK 100352         // 32*3136 = 784*128
#define QKVW 768

// =====================================================================
// GEMM core: 128x128 tile, BK=64, 256 threads (4 waves 2x2 of 64x64),
// mfma_f32_16x16x32_bf16, acc[4][4].
// R9 == R7 resubmit x2 (T4 counted vmcnt; R7/R8 benches were infra
// failures -- container crash, then broker capacity timeout).
// Per K-step: issue 8 prefetch loads for tile t+1 -> buf^1, then
// s_waitcnt vmcnt(8) (waits ONLY for tile t's loads; the 8 just-issued
// stay in flight across the barrier), raw s_barrier, ds_read+MFMA on
// buf, raw s_barrier (WAR: all waves' ds_reads of buf done -- forced by
// MFMA lgkmcnt consumption -- before next step's prefetch overwrites).
// R1's __syncthreads() drained vmcnt(0) including the prefetch (m97
// ceiling); counted vmcnt gives each tile's loads a full compute phase
// to land (T4/m218: counted-vs-drain0 = +38..73%).
// LDS per buf 16KB chunk-planar: (k-chunk q in [0,8), row, j) at
// [(q*128+row)*8+j] = lane-contiguous order global_load_lds writes.
// XCD swizzle: xcd = id&7 owns y-band [xcd*98, xcd*98+98), x fastest ->
// N-tiles of a row-tile co-resident on one XCD sharing A in its L2.
// =====================================================================
template <int K, int XT>
__device__ __forceinline__ void gemm_core(const u16* __restrict__ A, const u16* __restrict__ Bt,
                                          u16* sA, u16* sB, f4 (&acc)[4][4],
                                          int& yo, int& xo) {
    const int id = blockIdx.x;
    const int xcd = id & 7, slot = id >> 3;
    const int y = xcd * 98 + slot / XT;
    const int x = slot % XT;
    yo = y; xo = x;
    const int tid = threadIdx.x;
    const int lane = tid & 63, wv = tid >> 6;
    const int wy = wv >> 1, wx = wv & 1;
    const int qd = lane >> 4, lr = lane & 15;
    const long row0 = (long)y * 128;
    const long col0 = (long)x * 128;

#pragma unroll
    for (int a = 0; a < 4; ++a)
#pragma unroll
        for (int b = 0; b < 4; ++b)
#pragma unroll
            for (int r = 0; r < 4; ++r) acc[a][b][r] = 0.f;

    // 128 rows x 64 k = 1024 16B-chunks per matrix -> 4 per thread
    const u16* ga[4];
    const u16* gb[4];
    int lo[4];
#pragma unroll
    for (int s = 0; s < 4; ++s) {
        int li = tid + 256 * s;
        ga[s] = A + (row0 + (li & 127)) * K + (li >> 7) * 8;
        gb[s] = Bt + (col0 + (li & 127)) * K + (li >> 7) * 8;
        lo[s] = li * 8;
    }

    // prologue: stage tile 0 into buffer 0 (8 loads outstanding)
#pragma unroll
    for (int s = 0; s < 4; ++s) {
        async16(ga[s], sA + lo[s]);
        async16(gb[s], sB + lo[s]);
        ga[s] += 64; gb[s] += 64;
    }

    const int NT = K / 64;
    int cur = 0;
    for (int t = 0; t < NT; ++t) {
        if (t + 1 < NT) {
            // issue tile t+1 into the other buffer (stays in flight across
            // the barrier -- vmcnt(8) below does NOT wait for these)
            const int nb = (cur ^ 1) * 8192;
#pragma unroll
            for (int s = 0; s < 4; ++s) {
                async16(ga[s], sA + nb + lo[s]);
                async16(gb[s], sB + nb + lo[s]);
                ga[s] += 64; gb[s] += 64;
            }
            asm volatile("s_waitcnt vmcnt(8)" ::: "memory");  // tile t landed
        } else {
            asm volatile("s_waitcnt vmcnt(0)" ::: "memory");  // last tile landed
        }
        __builtin_amdgcn_sched_barrier(0);   // keep ds_reads below the waitcnt
        __builtin_amdgcn_s_barrier();        // RAW: tile t visible to all waves
        const u16* cA = sA + cur * 8192;
        const u16* cB = sB + cur * 8192;
#pragma unroll
        for (int kk = 0; kk < 2; ++kk) {
            const int ao = ((kk * 4 + qd) * 128 + wy * 64 + lr) * 8;
            const int bo = ((kk * 4 + qd) * 128 + wx * 64 + lr) * 8;
            bf8 av[4], bv[4];
#pragma unroll
            for (int mt = 0; mt < 4; ++mt) av[mt] = *(const bf8*)(cA + ao + mt * 128);
#pragma unroll
            for (int nt = 0; nt < 4; ++nt) bv[nt] = *(const bf8*)(cB + bo + nt * 128);
            __builtin_amdgcn_s_setprio(1);
#pragma unroll
            for (int mt = 0; mt < 4; ++mt)
#pragma unroll
                for (int nt = 0; nt < 4; ++nt)
                    acc[mt][nt] = __builtin_amdgcn_mfma_f32_16x16x32_bf16(av[mt], bv[nt], acc[mt][nt], 0, 0, 0);
            __builtin_amdgcn_s_setprio(0);
        }
        if (t + 1 < NT) {
            // WAR: every wave's ds_reads of buf[cur] completed (consumed by
            // MFMA above) before any wave's next prefetch overwrites it.
            __builtin_amdgcn_sched_barrier(0);
            __builtin_amdgcn_s_barrier();
            cur ^= 1;
        }
    }
}

// windowed row -> token-major index (undo window partition + roll(+3))
__device__ __forceinline__ long wtok(int rw) {
    int win = rw / 49, n = rw - win * 49;
    int b = win >> 6, wrc = win & 63;
    int hp = (wrc >> 3) * 7 + n / 7;
    int wp = (wrc & 7) * 7 + n % 7;
    int h = hp + 3; if (h >= HH) h -= HH;
    int w = wp + 3; if (w >= HH) w -= HH;
    return (long)b * HWSZ + h * HH + w;
}

// ---------- GEMM 1: QKV = Yw @ qkv_w + qkv_b  (bf16 out, windowed rows) ----------
__global__ __launch_bounds__(256) void gemm_qkv_kernel(const u16* __restrict__ A, const u16* __restrict__ Bt,
                                                       const float* __restrict__ bias, u16* __restrict__ C) {
    __shared__ u16 sA[2 * 8192], sB[2 * 8192];
    f4 acc[4][4];
    int y, x;
    gemm_core<256, 6>(A, Bt, sA, sB, acc, y, x);
    const int tid = threadIdx.x, lane = tid & 63, wv = tid >> 6;
    const int wy = wv >> 1, wx = wv & 1, qd = lane >> 4, lr = lane & 15;
    const long row0 = (long)y * 128 + wy * 64 + qd * 4;
    const int col0 = x * 128 + wx * 64 + lr;
#pragma unroll
    for (int mt = 0; mt < 4; ++mt) {
        long rb = row0 + mt * 16;
#pragma unroll
        for (int nt = 0; nt < 4; ++nt) {
            int c = col0 + nt * 16;
            float bv = bias[c];
#pragma unroll
            for (int r = 0; r < 4; ++r) C[(rb + r) * QKVW + c] = f2b(acc[mt][nt][r] + bv);
        }
    }
}

// ---------- GEMM 2: x1 += unwindow(Ow @ proj_w + proj_b) ----------
__global__ __launch_bounds__(256) void gemm_proj_kernel(const u16* __restrict__ A, const u16* __restrict__ Bt,
                                                        const float* __restrict__ bias, float* __restrict__ x1) {
    __shared__ u16 sA[2 * 8192], sB[2 * 8192];
    f4 acc[4][4];
    int y, x;
    gemm_core<256, 2>(A, Bt, sA, sB, acc, y, x);
    const int tid = threadIdx.x, lane = tid & 63, wv = tid >> 6;
    const int wy = wv >> 1, wx = wv & 1, qd = lane >> 4, lr = lane & 15;
    const int row0 = y * 128 + wy * 64 + qd * 4;
    const int col0 = x * 128 + wx * 64 + lr;
#pragma unroll
    for (int mt = 0; mt < 4; ++mt) {
        long tk[4];
#pragma unroll
        for (int r = 0; r < 4; ++r) tk[r] = wtok(row0 + mt * 16 + r);
#pragma unroll
        for (int nt = 0; nt < 4; ++nt) {
            int c = col0 + nt * 16;
            float bv = bias[c];
#pragma unroll
            for (int r = 0; r < 4; ++r) x1[tk[r] * CH + c] += acc[mt][nt][r] + bv;
        }
    }
}

// ---------- GEMM 3: Hid = gelu(L2 @ w1 + b1) (bf16 out) ----------
__global__ __launch_bounds__(256) void gemm_mlp1_kernel(const u16* __restrict__ A, const u16* __restrict__ Bt,
                                                        const float* __restrict__ bias, u16* __restrict__ C) {
    __shared__ u16 sA[2 * 8192], sB[2 * 8192];
    f4 acc[4][4];
    int y, x;
    gemm_core<256, 8>(A, Bt, sA, sB, acc, y, x);
    const int tid = threadIdx.x, lane = tid & 63, wv = tid >> 6;
    const int wy = wv >> 1, wx = wv & 1, qd = lane >> 4, lr = lane & 15;
    const long row0 = (long)y * 128 + wy * 64 + qd * 4;
    const int col0 = x * 128 + wx * 64 + lr;
#pragma unroll
    for (int mt = 0; mt < 4; ++mt) {
        long rb = row0 + mt * 16;
#pragma unroll
        for (int nt = 0; nt < 4; ++nt) {
            int c = col0 + nt * 16;
            float bv = bias[c];
#pragma unroll
            for (int r = 0; r < 4; ++r)
                C[(rb + r) * 1024 + c] = f2b(fgelu(acc[mt][nt][r] + bv));
        }
    }
}

// ---------- GEMM 4: out(B,C,H,W) = transpose(x1 + Hid @ w2 + b2) ----------
__global__ __launch_bounds__(256) void gemm_mlp2_kernel(const u16* __restrict__ A, const u16* __restrict__ Bt,
                                                        const float* __restrict__ bias, const float* __restrict__ x1,
                                                        float* __restrict__ out) {
    __shared__ u16 sA[2 * 8192], sB[2 * 8192];
    f4 acc[4][4];
    int y, x;
    gemm_core<1024, 2>(A, Bt, sA, sB, acc, y, x);
    const int tid = threadIdx.x, lane = tid & 63, wv = tid >> 6;
    const int wy = wv >> 1, wx = wv & 1, qd = lane >> 4, lr = lane & 15;
    const long row0 = (long)y * 128 + wy * 64 + qd * 4;
    const int col0 = x * 128 + wx * 64 + lr;
#pragma unroll
    for (int mt = 0; mt < 4; ++mt) {
        long r0 = row0 + mt * 16;                 // token index, multiple of 4
        long b = r0 / HWSZ, hw = r0 - b * HWSZ;   // 3136%4==0 -> quad never crosses b
#pragma unroll
        for (int nt = 0; nt < 4; ++nt) {
            int c = col0 + nt * 16;
            float bv = bias[c];
            f4 o;
#pragma unroll
            for (int r = 0; r < 4; ++r) o[r] = acc[mt][nt][r] + bv + x1[(r0 + r) * CH + c];
            *(f4*)(out + (b * CH + c) * HWSZ + hw) = o;
        }
    }
}

// ---------- LN1 + roll(-3) + window partition; also writes f32 shortcut into x1 ----------
__global__ __launch_bounds__(256) void ln1_kernel(const float* __restrict__ x, const float* __restrict__ g,
                                                  const float* __restrict__ be, float* __restrict__ x1,
                                                  u16* __restrict__ Yw) {
    __shared__ float tile[32 * 257];
    __shared__ float red0[256], red1[256];
    __shared__ float smu[32], srs[32];
    const int tid = threadIdx.x;
    const int blk = blockIdx.x;
    const int b = blk / 98, hw0 = (blk - b * 98) * 32;
    const int ty = tid >> 5, tx = tid & 31;
    const float* xb = x + (size_t)b * (CH * HWSZ) + hw0 + tx;
    float s = 0.f, q = 0.f;
#pragma unroll
    for (int ci = 0; ci < 32; ++ci) {
        int c = ty + ci * 8;
        float v = xb[c * HWSZ];
        tile[tx * 257 + c] = v;
        s += v; q += v * v;
    }
    red0[tid] = s;
    red1[tid] = q;
    __syncthreads();
    if (tid < 32) {
        float ss = 0.f, qq = 0.f;
#pragma unroll
        for (int j = 0; j < 8; ++j) { ss += red0[j * 32 + tid]; qq += red1[j * 32 + tid]; }
        float mu = ss * (1.f / 256.f);
        float var = qq * (1.f / 256.f) - mu * mu;
        smu[tid] = mu;
        srs[tid] = rsqrtf(var + 1e-5f);
    }
    __syncthreads();
    const int cl = tid & 31, tg = tid >> 5;
#pragma unroll
    for (int it = 0; it < 4; ++it) {
        int tok = tg + it * 8;
        float mu = smu[tok], rs = srs[tok];
        int hw = hw0 + tok;
        int h = hw / HH, w = hw - h * HH;
        int hp = h - 3; if (hp < 0) hp += HH;
        int wp = w - 3; if (wp < 0) wp += HH;
        long t = (long)b * HWSZ + hw;
        long rowY = (((long)(b * 64 + (hp / 7) * 8 + wp / 7)) * 49 + (hp % 7) * 7 + (wp % 7)) * CH;
        float* xr = x1 + t * CH;
#pragma unroll
        for (int j = 0; j < 8; ++j) {
            int c = j * 32 + cl;
            float v = tile[tok * 257 + c];
            xr[c] = v;  // shortcut (pre-LN), token-major
            Yw[rowY + c] = f2b((v - mu) * rs * g[c] + be[c]);
        }
    }
}

// ---------- LN2: x1 (f32 token-major) -> bf16 ----------
__global__ __launch_bounds__(256) void ln2_kernel(const float* __restrict__ x1, const float* __restrict__ g,
                                                  const float* __restrict__ be, u16* __restrict__ L2) {
    const long t = (long)blockIdx.x * 4 + (threadIdx.x >> 6);
    const int lane = threadIdx.x & 63;
    const float4 v = *(const float4*)(x1 + t * CH + lane * 4);
    float s = v.x + v.y + v.z + v.w;
    float q = v.x * v.x + v.y * v.y + v.z * v.z + v.w * v.w;
#pragma unroll
    for (int m = 1; m < 64; m <<= 1) {
        s += __shfl_xor(s, m, 64);
        q += __shfl_xor(q, m, 64);
    }
    float mu = s * (1.f / 256.f);
    float rs = rsqrtf(q * (1.f / 256.f) - mu * mu + 1e-5f);
    const float4 gg = *(const float4*)(g + lane * 4);
    const float4 bb = *(const float4*)(be + lane * 4);
    ushort4 o;
    o.x = f2b((v.x - mu) * rs * gg.x + bb.x);
    o.y = f2b((v.y - mu) * rs * gg.y + bb.y);
    o.z = f2b((v.z - mu) * rs * gg.z + bb.z);
    o.w = f2b((v.w - mu) * rs * gg.w + bb.w);
    *(ushort4*)(L2 + t * CH + lane * 4) = o;
}

// ---------- MFMA attention: 1 wave per (window, head), 49 tokens padded to 64 ----------
__global__ __launch_bounds__(256) void attn_kernel(const u16* __restrict__ QKV, u16* __restrict__ Ow) {
    __shared__ __align__(16) u16 pbuf[4][64 * 72];  // per-wave P slab (9216 B)
    const int tid = threadIdx.x;
    const int lane = tid & 63, wv = tid >> 6;
    const int pair = blockIdx.x * 4 + wv;
    const int win = pair >> 3, hd = pair & 7;
    const int lr = lane & 15, qd = lane >> 4;
    const u16* base = QKV + (size_t)win * (49 * QKVW) + hd * 32;

    // --- S = Q K^T ---
    bf8 aq[4], bk[4];
#pragma unroll
    for (int t = 0; t < 4; ++t) {
        int rq = t * 16 + lr; if (rq > 48) rq = 48;           // clamp pad rows
        const u16* rp = base + (size_t)rq * QKVW + qd * 8;
        aq[t] = *(const bf8*)(rp);                            // Q
        bk[t] = *(const bf8*)(rp + 256);                      // K
    }
    f4 s[4][4];
#pragma unroll
    for (int mt = 0; mt < 4; ++mt)
#pragma unroll
        for (int nt = 0; nt < 4; ++nt) {
#pragma unroll
            for (int r = 0; r < 4; ++r) s[mt][nt][r] = 0.f;
            s[mt][nt] = __builtin_amdgcn_mfma_f32_16x16x32_bf16(aq[mt], bk[nt], s[mt][nt], 0, 0, 0);
        }

    // --- softmax over cols (0..48 valid), P -> LDS ---
    const float SC = 0.17677669529663687f;  // 1/sqrt(32)
    float inv[4][4];
    u16* slab = pbuf[wv];
#pragma unroll
    for (int mt = 0; mt < 4; ++mt)
#pragma unroll
        for (int r = 0; r < 4; ++r) {
            float v0 = s[mt][0][r] * SC;
            float v1 = s[mt][1][r] * SC;
            float v2 = s[mt][2][r] * SC;
            float v3 = (lr == 0) ? s[mt][3][r] * SC : -3e38f;  // col 48+lr >= 49 masked
            float mx = fmaxf(fmaxf(v0, v1), fmaxf(v2, v3));
#pragma unroll
            for (int m = 1; m < 16; m <<= 1) mx = fmaxf(mx, __shfl_xor(mx, m, 64));
            v0 = __expf(v0 - mx); v1 = __expf(v1 - mx);
            v2 = __expf(v2 - mx); v3 = __expf(v3 - mx);
            float den = (v0 + v1) + (v2 + v3);
#pragma unroll
            for (int m = 1; m < 16; m <<= 1) den += __shfl_xor(den, m, 64);
            inv[mt][r] = 1.f / den;
            u16* pr = slab + (mt * 16 + qd * 4 + r) * 72 + lr;
            pr[0] = f2b(v0); pr[16] = f2b(v1); pr[32] = f2b(v2); pr[48] = f2b(v3);
        }
    // no __syncthreads(): each wave reads only its own pbuf[wv] slab;
    // compiler lgkmcnt ordering covers ds_write -> ds_read within a wave.

    // --- O = P V ---
    f4 o[4][2];
#pragma unroll
    for (int mt = 0; mt < 4; ++mt)
#pragma unroll
        for (int nt = 0; nt < 2; ++nt)
#pragma unroll
            for (int r = 0; r < 4; ++r) o[mt][nt][r] = 0.f;
#pragma unroll
    for (int kt = 0; kt < 2; ++kt) {
        bf8 ap[4];
#pragma unroll
        for (int mt = 0; mt < 4; ++mt)
            ap[mt] = *(const bf8*)(slab + (mt * 16 + lr) * 72 + kt * 32 + qd * 8);
        bf8 bvv[2];
#pragma unroll
        for (int nt = 0; nt < 2; ++nt)
#pragma unroll
            for (int j = 0; j < 8; ++j) {
                int row = kt * 32 + qd * 8 + j; if (row > 48) row = 48;  // P=0 there anyway
                bvv[nt][j] = __builtin_bit_cast(__bf16, base[(size_t)row * QKVW + 512 + nt * 16 + lr]);
            }
#pragma unroll
        for (int mt = 0; mt < 4; ++mt)
#pragma unroll
            for (int nt = 0; nt < 2; ++nt)
                o[mt][nt] = __builtin_amdgcn_mfma_f32_16x16x32_bf16(ap[mt], bvv[nt], o[mt][nt], 0, 0, 0);
    }

    // --- store O (rows < 49) ---
#pragma unroll
    for (int mt = 0; mt < 4; ++mt)
#pragma unroll
        for (int r = 0; r < 4; ++r) {
            int row = mt * 16 + qd * 4 + r;
            if (row < 49) {
                u16* orow = Ow + ((size_t)win * 49 + row) * CH + hd * 32 + lr;
                orow[0]  = f2b(o[mt][0][r] * inv[mt][r]);
                orow[16] = f2b(o[mt][1][r] * inv[mt][r]);
            }
        }
}

// ---------- weight transpose: src[K][N] f32 -> dst[N][K] bf16, LDS 32x33 tile ----------
__global__ __launch_bounds__(256) void transp_kernel(const float* __restrict__ src, u16* __restrict__ dst,
                                                     int K, int N) {
    __shared__ float t[32][33];
    const int n0 = blockIdx.x * 32, k0 = blockIdx.y * 32;
    const int tx = threadIdx.x & 31, ty = threadIdx.x >> 5;
#pragma unroll
    for (int j = 0; j < 32; j += 8)
        t[ty + j][tx] = src[(size_t)(k0 + ty + j) * N + n0 + tx];
    __syncthreads();
#pragma unroll
    for (int j = 0; j < 32; j += 8)
        dst[(size_t)(n0 + ty + j) * K + k0 + tx] = f2b(t[tx][ty + j]);
}

extern "C" void kernel_launch(void* const* d_in, const int* in_sizes, int n_in,
                              void* d_out, int out_size, void* d_ws, size_t ws_size,
                              hipStream_t stream) {
    (void)in_sizes; (void)n_in; (void)out_size; (void)ws_size;
    const float* x      = (const float*)d_in[0];
    const float* n1_g   = (const float*)d_in[1];
    const float* n1_b   = (const float*)d_in[2];
    const float* qkv_w  = (const float*)d_in[3];
    const float* qkv_b  = (const float*)d_in[4];
    const float* proj_w = (const float*)d_in[5];
    const float* proj_b = (const float*)d_in[6];
    const float* n2_g   = (const float*)d_in[7];
    const float* n2_b   = (const float*)d_in[8];
    const float* mlp_w1 = (const float*)d_in[9];
    const float* mlp_b1 = (const float*)d_in[10];
    const float* mlp_w2 = (const float*)d_in[11];
    const float* mlp_b2 = (const float*)d_in[12];
    float* out = (float*)d_out;

    // ws carve. bufA multiplexes Yw -> Ow -> LN2out; bufB multiplexes QKV -> Hid.
    uint8_t* w = (uint8_t*)d_ws;
    u16* bufA = (u16*)(w);                                     //  51,380,224
    u16* bufB = (u16*)(w + 51380224);                          // 205,520,896
    float* x1 = (float*)(w + 51380224 + 205520896);            // 102,760,448
    u16* wq  = (u16*)(w + 359661568);
    u16* wp  = (u16*)(w + 360054784);
    u16* w1t = (u16*)(w + 360185856);
    u16* w2t = (u16*)(w + 360710144);

    transp_kernel<<<dim3(24, 8),  256, 0, stream>>>(qkv_w,  wq,  256, 768);
    transp_kernel<<<dim3(8, 8),   256, 0, stream>>>(proj_w, wp,  256, 256);
    transp_kernel<<<dim3(32, 8),  256, 0, stream>>>(mlp_w1, w1t, 256, 1024);
    transp_kernel<<<dim3(8, 32),  256, 0, stream>>>(mlp_w2, w2t, 1024, 256);
    ln1_kernel<<<3136, 256, 0, stream>>>(x, n1_g, n1_b, x1, bufA);
    gemm_qkv_kernel<<<6 * 784, 256, 0, stream>>>(bufA, wq, qkv_b, bufB);
    attn_kernel<<<4096, 256, 0, stream>>>(bufB, bufA);
    gemm_proj_kernel<<<2 * 784, 256, 0, stream>>>(bufA, wp, proj_b, x1);
    ln2_kernel<<<25088, 256, 0, stream>>>(x1, n2_g, n2_b, bufA);
    gemm_mlp1_kernel<<<8 * 784, 256, 0, stream>>>(bufA, w1t, mlp_b1, bufB);
    gemm_mlp2_kernel<<<2 * 784, 256, 0, stream>>>(bufB, w2t, mlp_b2, x1, out);
}

// Round 5
// 681.535 us; speedup vs baseline: 1.2733x; 1.2356x over previous
//
#include <hip/hip_runtime.h>
#include <cstdint>

typedef unsigned short u16;
typedef unsigned int u32;
typedef __bf16 bf8 __attribute__((ext_vector_type(8)));
typedef float f4 __attribute__((ext_vector_type(4)));

// ---------- bf16 helpers (bit-level, RNE) ----------
__device__ __forceinline__ u16 f2b(float f) {
    u32 u = __builtin_bit_cast(u32, f);
    u += 0x7fffu + ((u >> 16) & 1u);
    return (u16)(u >> 16);
}

// fast GELU: tanh approximation in sigmoid form (max err ~3e-3 << 0.135 thr)
__device__ __forceinline__ float fgelu(float u) {
    float t = u * (1.5957691216057308f + 0.07135481627859035f * u * u);
    return u / (1.f + __expf(-t));
}

// ---------- async global->LDS, 16B per lane ----------
__device__ __forceinline__ void async16(const u16* g, u16* l) {
    auto gp = (const __attribute__((address_space(1))) u32*)(uintptr_t)g;
    auto lp = (__attribute__((address_space(3))) u32*)(uintptr_t)l;
    __builtin_amdgcn_global_load_lds(gp, lp, 16, 0, 0);
}

// ---------- problem constants ----------
#define CH 256
#define HH 56
#define HWSZ 3136          // 56*56
#define TOK 100352         // 32*3136 = 784*128
#define QKVW 768

// =====================================================================
// GEMM core: 128x128 tile, BK=64, 256 threads (4 waves 2x2 of 64x64),
// mfma_f32_16x16x32_bf16, acc[4][4].
// R10: COALESCED staging (the R4 counters showed all pipes idle with
// loads stalled: old mapping row=li&127 made each global_load_lds a
// 64-row gather at stride K*2B = up to 64 cache lines/instr; TA
// transaction throughput was the real bottleneck, not pipeline depth).
// New mapping (rule #21: linear LDS dest + inverse-swizzled SOURCE +
// swizzled read): thread li stages row=li>>3, LDS slot=li&7, loading
// global chunk (li&7)^(row&7). Wave = 8 rows x 128B contiguous = 16
// lines (4x fewer transactions). LDS layout: [row][slot] u16[128][64]
// where slot s holds global chunk s^(row&7) (byte ^= (row&7)<<4).
// ds_read of chunk c: slot c^(row&7); row&7==lr&7 for fragment rows ->
// 8 consecutive rows hit all 8 slots = bandwidth-minimal, no conflict.
// T4 counted-vmcnt pipeline kept: issue tile t+1, s_waitcnt vmcnt(8)
// (only tile t), s_barrier, MFMA, s_barrier (WAR), flip.
// XCD swizzle: xcd = id&7 owns y-band [xcd*98, xcd*98+98), x fastest.
// =====================================================================
template <int K, int XT>
__device__ __forceinline__ void gemm_core(const u16* __restrict__ A, const u16* __restrict__ Bt,
                                          u16* sA, u16* sB, f4 (&acc)[4][4],
                                          int& yo, int& xo) {
    const int id = blockIdx.x;
    const int xcd = id & 7, slot = id >> 3;
    const int y = xcd * 98 + slot / XT;
    const int x = slot % XT;
    yo = y; xo = x;
    const int tid = threadIdx.x;
    const int lane = tid & 63, wv = tid >> 6;
    const int wy = wv >> 1, wx = wv & 1;
    const int qd = lane >> 4, lr = lane & 15;
    const long row0 = (long)y * 128;
    const long col0 = (long)x * 128;

#pragma unroll
    for (int a = 0; a < 4; ++a)
#pragma unroll
        for (int b = 0; b < 4; ++b)
#pragma unroll
            for (int r = 0; r < 4; ++r) acc[a][b][r] = 0.f;

    // 128 rows x 8 chunks (16B) per matrix = 1024 chunks -> 4 per thread.
    // Thread li -> LDS u16 offset li*8 (linear); global chunk XOR-swizzled.
    const u16* ga[4];
    const u16* gb[4];
    int lo[4];
#pragma unroll
    for (int s = 0; s < 4; ++s) {
        int li = tid + 256 * s;
        int row = li >> 3;
        int ck = (li & 7) ^ (row & 7);          // inverse-swizzled source chunk
        ga[s] = A + (row0 + row) * K + ck * 8;
        gb[s] = Bt + (col0 + row) * K + ck * 8;
        lo[s] = li * 8;
    }

    // prologue: stage tile 0 into buffer 0 (8 loads outstanding)
#pragma unroll
    for (int s = 0; s < 4; ++s) {
        async16(ga[s], sA + lo[s]);
        async16(gb[s], sB + lo[s]);
        ga[s] += 64; gb[s] += 64;
    }

    const int NT = K / 64;
    int cur = 0;
    for (int t = 0; t < NT; ++t) {
        if (t + 1 < NT) {
            // issue tile t+1 into the other buffer (stays in flight across
            // the barrier -- vmcnt(8) below does NOT wait for these)
            const int nb = (cur ^ 1) * 8192;
#pragma unroll
            for (int s = 0; s < 4; ++s) {
                async16(ga[s], sA + nb + lo[s]);
                async16(gb[s], sB + nb + lo[s]);
                ga[s] += 64; gb[s] += 64;
            }
            asm volatile("s_waitcnt vmcnt(8)" ::: "memory");  // tile t landed
        } else {
            asm volatile("s_waitcnt vmcnt(0)" ::: "memory");  // last tile landed
        }
        __builtin_amdgcn_sched_barrier(0);   // keep ds_reads below the waitcnt
        __builtin_amdgcn_s_barrier();        // RAW: tile t visible to all waves
        const u16* cA = sA + cur * 8192;
        const u16* cB = sB + cur * 8192;
        const int arow = wy * 64 + lr;       // fragment base row (A side)
        const int brow = wx * 64 + lr;       // fragment base row (B side)
#pragma unroll
        for (int kk = 0; kk < 2; ++kk) {
            const int c = kk * 4 + qd;                  // k-chunk wanted
            const int asw = ((c ^ (lr & 7)) * 8);       // swizzled slot (u16)
            bf8 av[4], bv[4];
#pragma unroll
            for (int mt = 0; mt < 4; ++mt) av[mt] = *(const bf8*)(cA + arow * 64 + mt * 1024 + asw);
#pragma unroll
            for (int nt = 0; nt < 4; ++nt) bv[nt] = *(const bf8*)(cB + brow * 64 + nt * 1024 + asw);
            __builtin_amdgcn_s_setprio(1);
#pragma unroll
            for (int mt = 0; mt < 4; ++mt)
#pragma unroll
                for (int nt = 0; nt < 4; ++nt)
                    acc[mt][nt] = __builtin_amdgcn_mfma_f32_16x16x32_bf16(av[mt], bv[nt], acc[mt][nt], 0, 0, 0);
            __builtin_amdgcn_s_setprio(0);
        }
        if (t + 1 < NT) {
            // WAR: every wave's ds_reads of buf[cur] completed (consumed by
            // MFMA above) before any wave's next prefetch overwrites it.
            __builtin_amdgcn_sched_barrier(0);
            __builtin_amdgcn_s_barrier();
            cur ^= 1;
        }
    }
}

// windowed row -> token-major index (undo window partition + roll(+3))
__device__ __forceinline__ long wtok(int rw) {
    int win = rw / 49, n = rw - win * 49;
    int b = win >> 6, wrc = win & 63;
    int hp = (wrc >> 3) * 7 + n / 7;
    int wp = (wrc & 7) * 7 + n % 7;
    int h = hp + 3; if (h >= HH) h -= HH;
    int w = wp + 3; if (w >= HH) w -= HH;
    return (long)b * HWSZ + h * HH + w;
}

// ---------- GEMM 1: QKV = Yw @ qkv_w + qkv_b  (bf16 out, windowed rows) ----------
__global__ __launch_bounds__(256) void gemm_qkv_kernel(const u16* __restrict__ A, const u16* __restrict__ Bt,
                                                       const float* __restrict__ bias, u16* __restrict__ C) {
    __shared__ u16 sA[2 * 8192], sB[2 * 8192];
    f4 acc[4][4];
    int y, x;
    gemm_core<256, 6>(A, Bt, sA, sB, acc, y, x);
    const int tid = threadIdx.x, lane = tid & 63, wv = tid >> 6;
    const int wy = wv >> 1, wx = wv & 1, qd = lane >> 4, lr = lane & 15;
    const long row0 = (long)y * 128 + wy * 64 + qd * 4;
    const int col0 = x * 128 + wx * 64 + lr;
#pragma unroll
    for (int mt = 0; mt < 4; ++mt) {
        long rb = row0 + mt * 16;
#pragma unroll
        for (int nt = 0; nt < 4; ++nt) {
            int c = col0 + nt * 16;
            float bv = bias[c];
#pragma unroll
            for (int r = 0; r < 4; ++r) C[(rb + r) * QKVW + c] = f2b(acc[mt][nt][r] + bv);
        }
    }
}

// ---------- GEMM 2: x1 += unwindow(Ow @ proj_w + proj_b) ----------
__global__ __launch_bounds__(256) void gemm_proj_kernel(const u16* __restrict__ A, const u16* __restrict__ Bt,
                                                        const float* __restrict__ bias, float* __restrict__ x1) {
    __shared__ u16 sA[2 * 8192], sB[2 * 8192];
    f4 acc[4][4];
    int y, x;
    gemm_core<256, 2>(A, Bt, sA, sB, acc, y, x);
    const int tid = threadIdx.x, lane = tid & 63, wv = tid >> 6;
    const int wy = wv >> 1, wx = wv & 1, qd = lane >> 4, lr = lane & 15;
    const int row0 = y * 128 + wy * 64 + qd * 4;
    const int col0 = x * 128 + wx * 64 + lr;
#pragma unroll
    for (int mt = 0; mt < 4; ++mt) {
        long tk[4];
#pragma unroll
        for (int r = 0; r < 4; ++r) tk[r] = wtok(row0 + mt * 16 + r);
#pragma unroll
        for (int nt = 0; nt < 4; ++nt) {
            int c = col0 + nt * 16;
            float bv = bias[c];
#pragma unroll
            for (int r = 0; r < 4; ++r) x1[tk[r] * CH + c] += acc[mt][nt][r] + bv;
        }
    }
}

// ---------- GEMM 3: Hid = gelu(L2 @ w1 + b1) (bf16 out) ----------
__global__ __launch_bounds__(256) void gemm_mlp1_kernel(const u16* __restrict__ A, const u16* __restrict__ Bt,
                                                        const float* __restrict__ bias, u16* __restrict__ C) {
    __shared__ u16 sA[2 * 8192], sB[2 * 8192];
    f4 acc[4][4];
    int y, x;
    gemm_core<256, 8>(A, Bt, sA, sB, acc, y, x);
    const int tid = threadIdx.x, lane = tid & 63, wv = tid >> 6;
    const int wy = wv >> 1, wx = wv & 1, qd = lane >> 4, lr = lane & 15;
    const long row0 = (long)y * 128 + wy * 64 + qd * 4;
    const int col0 = x * 128 + wx * 64 + lr;
#pragma unroll
    for (int mt = 0; mt < 4; ++mt) {
        long rb = row0 + mt * 16;
#pragma unroll
        for (int nt = 0; nt < 4; ++nt) {
            int c = col0 + nt * 16;
            float bv = bias[c];
#pragma unroll
            for (int r = 0; r < 4; ++r)
                C[(rb + r) * 1024 + c] = f2b(fgelu(acc[mt][nt][r] + bv));
        }
    }
}

// ---------- GEMM 4: out(B,C,H,W) = transpose(x1 + Hid @ w2 + b2) ----------
__global__ __launch_bounds__(256) void gemm_mlp2_kernel(const u16* __restrict__ A, const u16* __restrict__ Bt,
                                                        const float* __restrict__ bias, const float* __restrict__ x1,
                                                        float* __restrict__ out) {
    __shared__ u16 sA[2 * 8192], sB[2 * 8192];
    f4 acc[4][4];
    int y, x;
    gemm_core<1024, 2>(A, Bt, sA, sB, acc, y, x);
    const int tid = threadIdx.x, lane = tid & 63, wv = tid >> 6;
    const int wy = wv >> 1, wx = wv & 1, qd = lane >> 4, lr = lane & 15;
    const long row0 = (long)y * 128 + wy * 64 + qd * 4;
    const int col0 = x * 128 + wx * 64 + lr;
#pragma unroll
    for (int mt = 0; mt < 4; ++mt) {
        long r0 = row0 + mt * 16;                 // token index, multiple of 4
        long b = r0 / HWSZ, hw = r0 - b * HWSZ;   // 3136%4==0 -> quad never crosses b
#pragma unroll
        for (int nt = 0; nt < 4; ++nt) {
            int c = col0 + nt * 16;
            float bv = bias[c];
            f4 o;
#pragma unroll
            for (int r = 0; r < 4; ++r) o[r] = acc[mt][nt][r] + bv + x1[(r0 + r) * CH + c];
            *(f4*)(out + (b * CH + c) * HWSZ + hw) = o;
        }
    }
}

// ---------- LN1 + roll(-3) + window partition; also writes f32 shortcut into x1 ----------
__global__ __launch_bounds__(256) void ln1_kernel(const float* __restrict__ x, const float* __restrict__ g,
                                                  const float* __restrict__ be, float* __restrict__ x1,
                                                  u16* __restrict__ Yw) {
    __shared__ float tile[32 * 257];
    __shared__ float red0[256], red1[256];
    __shared__ float smu[32], srs[32];
    const int tid = threadIdx.x;
    const int blk = blockIdx.x;
    const int b = blk / 98, hw0 = (blk - b * 98) * 32;
    const int ty = tid >> 5, tx = tid & 31;
    const float* xb = x + (size_t)b * (CH * HWSZ) + hw0 + tx;
    float s = 0.f, q = 0.f;
#pragma unroll
    for (int ci = 0; ci < 32; ++ci) {
        int c = ty + ci * 8;
        float v = xb[c * HWSZ];
        tile[tx * 257 + c] = v;
        s += v; q += v * v;
    }
    red0[tid] = s;
    red1[tid] = q;
    __syncthreads();
    if (tid < 32) {
        float ss = 0.f, qq = 0.f;
#pragma unroll
        for (int j = 0; j < 8; ++j) { ss += red0[j * 32 + tid]; qq += red1[j * 32 + tid]; }
        float mu = ss * (1.f / 256.f);
        float var = qq * (1.f / 256.f) - mu * mu;
        smu[tid] = mu;
        srs[tid] = rsqrtf(var + 1e-5f);
    }
    __syncthreads();
    const int cl = tid & 31, tg = tid >> 5;
#pragma unroll
    for (int it = 0; it < 4; ++it) {
        int tok = tg + it * 8;
        float mu = smu[tok], rs = srs[tok];
        int hw = hw0 + tok;
        int h = hw / HH, w = hw - h * HH;
        int hp = h - 3; if (hp < 0) hp += HH;
        int wp = w - 3; if (wp < 0) wp += HH;
        long t = (long)b * HWSZ + hw;
        long rowY = (((long)(b * 64 + (hp / 7) * 8 + wp / 7)) * 49 + (hp % 7) * 7 + (wp % 7)) * CH;
        float* xr = x1 + t * CH;
#pragma unroll
        for (int j = 0; j < 8; ++j) {
            int c = j * 32 + cl;
            float v = tile[tok * 257 + c];
            xr[c] = v;  // shortcut (pre-LN), token-major
            Yw[rowY + c] = f2b((v - mu) * rs * g[c] + be[c]);
        }
    }
}

// ---------- LN2: x1 (f32 token-major) -> bf16 ----------
__global__ __launch_bounds__(256) void ln2_kernel(const float* __restrict__ x1, const float* __restrict__ g,
                                                  const float* __restrict__ be, u16* __restrict__ L2) {
    const long t = (long)blockIdx.x * 4 + (threadIdx.x >> 6);
    const int lane = threadIdx.x & 63;
    const float4 v = *(const float4*)(x1 + t * CH + lane * 4);
    float s = v.x + v.y + v.z + v.w;
    float q = v.x * v.x + v.y * v.y + v.z * v.z + v.w * v.w;
#pragma unroll
    for (int m = 1; m < 64; m <<= 1) {
        s += __shfl_xor(s, m, 64);
        q += __shfl_xor(q, m, 64);
    }
    float mu = s * (1.f / 256.f);
    float rs = rsqrtf(q * (1.f / 256.f) - mu * mu + 1e-5f);
    const float4 gg = *(const float4*)(g + lane * 4);
    const float4 bb = *(const float4*)(be + lane * 4);
    ushort4 o;
    o.x = f2b((v.x - mu) * rs * gg.x + bb.x);
    o.y = f2b((v.y - mu) * rs * gg.y + bb.y);
    o.z = f2b((v.z - mu) * rs * gg.z + bb.z);
    o.w = f2b((v.w - mu) * rs * gg.w + bb.w);
    *(ushort4*)(L2 + t * CH + lane * 4) = o;
}

// ---------- MFMA attention: 1 wave per (window, head), 49 tokens padded to 64 ----------
__global__ __launch_bounds__(256) void attn_kernel(const u16* __restrict__ QKV, u16* __restrict__ Ow) {
    __shared__ __align__(16) u16 pbuf[4][64 * 72];  // per-wave P slab (9216 B)
    const int tid = threadIdx.x;
    const int lane = tid & 63, wv = tid >> 6;
    const int pair = blockIdx.x * 4 + wv;
    const int win = pair >> 3, hd = pair & 7;
    const int lr = lane & 15, qd = lane >> 4;
    const u16* base = QKV + (size_t)win * (49 * QKVW) + hd * 32;

    // --- S = Q K^T ---
    bf8 aq[4], bk[4];
#pragma unroll
    for (int t = 0; t < 4; ++t) {
        int rq = t * 16 + lr; if (rq > 48) rq = 48;           // clamp pad rows
        const u16* rp = base + (size_t)rq * QKVW + qd * 8;
        aq[t] = *(const bf8*)(rp);                            // Q
        bk[t] = *(const bf8*)(rp + 256);                      // K
    }
    f4 s[4][4];
#pragma unroll
    for (int mt = 0; mt < 4; ++mt)
#pragma unroll
        for (int nt = 0; nt < 4; ++nt) {
#pragma unroll
            for (int r = 0; r < 4; ++r) s[mt][nt][r] = 0.f;
            s[mt][nt] = __builtin_amdgcn_mfma_f32_16x16x32_bf16(aq[mt], bk[nt], s[mt][nt], 0, 0, 0);
        }

    // --- softmax over cols (0..48 valid), P -> LDS ---
    const float SC = 0.17677669529663687f;  // 1/sqrt(32)
    float inv[4][4];
    u16* slab = pbuf[wv];
#pragma unroll
    for (int mt = 0; mt < 4; ++mt)
#pragma unroll
        for (int r = 0; r < 4; ++r) {
            float v0 = s[mt][0][r] * SC;
            float v1 = s[mt][1][r] * SC;
            float v2 = s[mt][2][r] * SC;
            float v3 = (lr == 0) ? s[mt][3][r] * SC : -3e38f;  // col 48+lr >= 49 masked
            float mx = fmaxf(fmaxf(v0, v1), fmaxf(v2, v3));
#pragma unroll
            for (int m = 1; m < 16; m <<= 1) mx = fmaxf(mx, __shfl_xor(mx, m, 64));
            v0 = __expf(v0 - mx); v1 = __expf(v1 - mx);
            v2 = __expf(v2 - mx); v3 = __expf(v3 - mx);
            float den = (v0 + v1) + (v2 + v3);
#pragma unroll
            for (int m = 1; m < 16; m <<= 1) den += __shfl_xor(den, m, 64);
            inv[mt][r] = 1.f / den;
            u16* pr = slab + (mt * 16 + qd * 4 + r) * 72 + lr;
            pr[0] = f2b(v0); pr[16] = f2b(v1); pr[32] = f2b(v2); pr[48] = f2b(v3);
        }
    // no __syncthreads(): each wave reads only its own pbuf[wv] slab;
    // compiler lgkmcnt ordering covers ds_write -> ds_read within a wave.

    // --- O = P V ---
    f4 o[4][2];
#pragma unroll
    for (int mt = 0; mt < 4; ++mt)
#pragma unroll
        for (int nt = 0; nt < 2; ++nt)
#pragma unroll
            for (int r = 0; r < 4; ++r) o[mt][nt][r] = 0.f;
#pragma unroll
    for (int kt = 0; kt < 2; ++kt) {
        bf8 ap[4];
#pragma unroll
        for (int mt = 0; mt < 4; ++mt)
            ap[mt] = *(const bf8*)(slab + (mt * 16 + lr) * 72 + kt * 32 + qd * 8);
        bf8 bvv[2];
#pragma unroll
        for (int nt = 0; nt < 2; ++nt)
#pragma unroll
            for (int j = 0; j < 8; ++j) {
                int row = kt * 32 + qd * 8 + j; if (row > 48) row = 48;  // P=0 there anyway
                bvv[nt][j] = __builtin_bit_cast(__bf16, base[(size_t)row * QKVW + 512 + nt * 16 + lr]);
            }
#pragma unroll
        for (int mt = 0; mt < 4; ++mt)
#pragma unroll
            for (int nt = 0; nt < 2; ++nt)
                o[mt][nt] = __builtin_amdgcn_mfma_f32_16x16x32_bf16(ap[mt], bvv[nt], o[mt][nt], 0, 0, 0);
    }

    // --- store O (rows < 49) ---
#pragma unroll
    for (int mt = 0; mt < 4; ++mt)
#pragma unroll
        for (int r = 0; r < 4; ++r) {
            int row = mt * 16 + qd * 4 + r;
            if (row < 49) {
                u16* orow = Ow + ((size_t)win * 49 + row) * CH + hd * 32 + lr;
                orow[0]  = f2b(o[mt][0][r] * inv[mt][r]);
                orow[16] = f2b(o[mt][1][r] * inv[mt][r]);
            }
        }
}

// ---------- weight transpose: src[K][N] f32 -> dst[N][K] bf16, LDS 32x33 tile ----------
__global__ __launch_bounds__(256) void transp_kernel(const float* __restrict__ src, u16* __restrict__ dst,
                                                     int K, int N) {
    __shared__ float t[32][33];
    const int n0 = blockIdx.x * 32, k0 = blockIdx.y * 32;
    const int tx = threadIdx.x & 31, ty = threadIdx.x >> 5;
#pragma unroll
    for (int j = 0; j < 32; j += 8)
        t[ty + j][tx] = src[(size_t)(k0 + ty + j) * N + n0 + tx];
    __syncthreads();
#pragma unroll
    for (int j = 0; j < 32; j += 8)
        dst[(size_t)(n0 + ty + j) * K + k0 + tx] = f2b(t[tx][ty + j]);
}

extern "C" void kernel_launch(void* const* d_in, const int* in_sizes, int n_in,
                              void* d_out, int out_size, void* d_ws, size_t ws_size,
                              hipStream_t stream) {
    (void)in_sizes; (void)n_in; (void)out_size; (void)ws_size;
    const float* x      = (const float*)d_in[0];
    const float* n1_g   = (const float*)d_in[1];
    const float* n1_b   = (const float*)d_in[2];
    const float* qkv_w  = (const float*)d_in[3];
    const float* qkv_b  = (const float*)d_in[4];
    const float* proj_w = (const float*)d_in[5];
    const float* proj_b = (const float*)d_in[6];
    const float* n2_g   = (const float*)d_in[7];
    const float* n2_b   = (const float*)d_in[8];
    const float* mlp_w1 = (const float*)d_in[9];
    const float* mlp_b1 = (const float*)d_in[10];
    const float* mlp_w2 = (const float*)d_in[11];
    const float* mlp_b2 = (const float*)d_in[12];
    float* out = (float*)d_out;

    // ws carve. bufA multiplexes Yw -> Ow -> LN2out; bufB multiplexes QKV -> Hid.
    uint8_t* w = (uint8_t*)d_ws;
    u16* bufA = (u16*)(w);                                     //  51,380,224
    u16* bufB = (u16*)(w + 51380224);                          // 205,520,896
    float* x1 = (float*)(w + 51380224 + 205520896);            // 102,760,448
    u16* wq  = (u16*)(w + 359661568);
    u16* wp  = (u16*)(w + 360054784);
    u16* w1t = (u16*)(w + 360185856);
    u16* w2t = (u16*)(w + 360710144);

    transp_kernel<<<dim3(24, 8),  256, 0, stream>>>(qkv_w,  wq,  256, 768);
    transp_kernel<<<dim3(8, 8),   256, 0, stream>>>(proj_w, wp,  256, 256);
    transp_kernel<<<dim3(32, 8),  256, 0, stream>>>(mlp_w1, w1t, 256, 1024);
    transp_kernel<<<dim3(8, 32),  256, 0, stream>>>(mlp_w2, w2t, 1024, 256);
    ln1_kernel<<<3136, 256, 0, stream>>>(x, n1_g, n1_b, x1, bufA);
    gemm_qkv_kernel<<<6 * 784, 256, 0, stream>>>(bufA, wq, qkv_b, bufB);
    attn_kernel<<<4096, 256, 0, stream>>>(bufB, bufA);
    gemm_proj_kernel<<<2 * 784, 256, 0, stream>>>(bufA, wp, proj_b, x1);
    ln2_kernel<<<25088, 256, 0, stream>>>(x1, n2_g, n2_b, bufA);
    gemm_mlp1_kernel<<<8 * 784, 256, 0, stream>>>(bufA, w1t, mlp_b1, bufB);
    gemm_mlp2_kernel<<<2 * 784, 256, 0, stream>>>(bufB, w2t, mlp_b2, x1, out);
}

// Round 6
// 675.786 us; speedup vs baseline: 1.2842x; 1.0085x over previous
//
#include <hip/hip_runtime.h>
#include <cstdint>

typedef unsigned short u16;
typedef unsigned int u32;
typedef __bf16 bf8 __attribute__((ext_vector_type(8)));
typedef float f4 __attribute__((ext_vector_type(4)));

// ---------- bf16 helpers (bit-level, RNE) ----------
__device__ __forceinline__ u16 f2b(float f) {
    u32 u = __builtin_bit_cast(u32, f);
    u += 0x7fffu + ((u >> 16) & 1u);
    return (u16)(u >> 16);
}

// fast GELU: tanh approximation in sigmoid form (max err ~3e-3 << 0.135 thr)
__device__ __forceinline__ float fgelu(float u) {
    float t = u * (1.5957691216057308f + 0.07135481627859035f * u * u);
    return u / (1.f + __expf(-t));
}

// ---------- async global->LDS, 16B per lane ----------
__device__ __forceinline__ void async16(const u16* g, u16* l) {
    auto gp = (const __attribute__((address_space(1))) u32*)(uintptr_t)g;
    auto lp = (__attribute__((address_space(3))) u32*)(uintptr_t)l;
    __builtin_amdgcn_global_load_lds(gp, lp, 16, 0, 0);
}

// ---------- problem constants ----------
#define CH 256
#define HH 56
#define HWSZ 3136          // 56*56
#define TOK 100352         // 32*3136 = 784*128
#define QKVW 768

// =====================================================================
// GEMM core: 128x128 tile, BK=32, 256 threads (4 waves 2x2 of 64x64),
// mfma_f32_16x16x32_bf16, acc[4][4].
// R11: OCCUPANCY (short-K fix). R5 counters: mlp1 Occ 20.7% (2-block
// LDS cap), MfmaUtil 15.4% = exactly the compute floor, all pipes idle
// -> per-block prologue (HBM first-tile wait) + epilogue (gelu+stores)
// dominate at NT=4 and 2 blocks/CU can't overlap them. BK 64->32
// halves LDS to 32KB/block -> LDS cap 5 blocks/CU; launch_bounds
// (256,4) caps VGPR at 128 -> 4-5 blocks resident, 2-2.5x waves.
// Per K-step: 4 async16/thread (A 8KB + B 8KB), counted s_waitcnt
// vmcnt(4), raw s_barrier, 8 ds_read_b128 + 16 MFMA, s_barrier (WAR).
// Coalescing kept: wave stages 16 rows x 64B contiguous.
// LDS swizzle (both-sides, rule #21): linear LDS dest; source chunk
// ck = sl ^ (row&3) ^ ((row>>2)&3); read slot = qd ^ (lr&3) ^
// ((lr>>2)&3) (row low-4-bits == lr for all fragment rows). Bank map
// v(a,b) = 16(b&1) + 4(a^b) over 16 rows -> exact 2-way everywhere =
// free (m136).
// XCD swizzle: xcd = id&7 owns y-band [xcd*98, xcd*98+98), x fastest.
// =====================================================================
template <int K, int XT>
__device__ __forceinline__ void gemm_core(const u16* __restrict__ A, const u16* __restrict__ Bt,
                                          u16* sA, u16* sB, f4 (&acc)[4][4],
                                          int& yo, int& xo) {
    const int id = blockIdx.x;
    const int xcd = id & 7, slot = id >> 3;
    const int y = xcd * 98 + slot / XT;
    const int x = slot % XT;
    yo = y; xo = x;
    const int tid = threadIdx.x;
    const int lane = tid & 63, wv = tid >> 6;
    const int wy = wv >> 1, wx = wv & 1;
    const int qd = lane >> 4, lr = lane & 15;
    const long row0 = (long)y * 128;
    const long col0 = (long)x * 128;

#pragma unroll
    for (int a = 0; a < 4; ++a)
#pragma unroll
        for (int b = 0; b < 4; ++b)
#pragma unroll
            for (int r = 0; r < 4; ++r) acc[a][b][r] = 0.f;

    // 128 rows x 4 chunks (16B) per matrix = 512 chunks -> 2 per thread.
    // Thread li -> LDS u16 offset li*8 (linear); global chunk XOR-swizzled.
    const u16* ga[2];
    const u16* gb[2];
    int lo[2];
#pragma unroll
    for (int s = 0; s < 2; ++s) {
        int li = tid + 256 * s;
        int row = li >> 2;
        int ck = (li & 3) ^ (row & 3) ^ ((row >> 2) & 3);   // inverse-swizzled source chunk
        ga[s] = A + (row0 + row) * K + ck * 8;
        gb[s] = Bt + (col0 + row) * K + ck * 8;
        lo[s] = li * 8;
    }

    // prologue: stage tile 0 into buffer 0 (4 loads outstanding)
#pragma unroll
    for (int s = 0; s < 2; ++s) {
        async16(ga[s], sA + lo[s]);
        async16(gb[s], sB + lo[s]);
        ga[s] += 32; gb[s] += 32;
    }

    const int NT = K / 32;
    int cur = 0;
    // lane-constant swizzled slot (u16 units): same for every fragment row
    const int sw8 = ((qd ^ (lr & 3) ^ ((lr >> 2) & 3)) * 8);
    const int arow = (wy * 64 + lr) * 32;    // A fragment base (u16)
    const int brow = (wx * 64 + lr) * 32;    // B fragment base (u16)
    for (int t = 0; t < NT; ++t) {
        if (t + 1 < NT) {
            // issue tile t+1 into the other buffer (stays in flight across
            // the barrier -- vmcnt(4) below does NOT wait for these)
            const int nb = (cur ^ 1) * 4096;
#pragma unroll
            for (int s = 0; s < 2; ++s) {
                async16(ga[s], sA + nb + lo[s]);
                async16(gb[s], sB + nb + lo[s]);
                ga[s] += 32; gb[s] += 32;
            }
            asm volatile("s_waitcnt vmcnt(4)" ::: "memory");  // tile t landed
        } else {
            asm volatile("s_waitcnt vmcnt(0)" ::: "memory");  // last tile landed
        }
        __builtin_amdgcn_sched_barrier(0);   // keep ds_reads below the waitcnt
        __builtin_amdgcn_s_barrier();        // RAW: tile t visible to all waves
        const u16* cA = sA + cur * 4096;
        const u16* cB = sB + cur * 4096;
        bf8 av[4], bv[4];
#pragma unroll
        for (int mt = 0; mt < 4; ++mt) av[mt] = *(const bf8*)(cA + arow + mt * 512 + sw8);
#pragma unroll
        for (int nt = 0; nt < 4; ++nt) bv[nt] = *(const bf8*)(cB + brow + nt * 512 + sw8);
        __builtin_amdgcn_s_setprio(1);
#pragma unroll
        for (int mt = 0; mt < 4; ++mt)
#pragma unroll
            for (int nt = 0; nt < 4; ++nt)
                acc[mt][nt] = __builtin_amdgcn_mfma_f32_16x16x32_bf16(av[mt], bv[nt], acc[mt][nt], 0, 0, 0);
        __builtin_amdgcn_s_setprio(0);
        if (t + 1 < NT) {
            // WAR: every wave's ds_reads of buf[cur] completed (consumed by
            // MFMA above) before any wave's next prefetch overwrites it.
            __builtin_amdgcn_sched_barrier(0);
            __builtin_amdgcn_s_barrier();
            cur ^= 1;
        }
    }
}

// windowed row -> token-major index (undo window partition + roll(+3))
__device__ __forceinline__ long wtok(int rw) {
    int win = rw / 49, n = rw - win * 49;
    int b = win >> 6, wrc = win & 63;
    int hp = (wrc >> 3) * 7 + n / 7;
    int wp = (wrc & 7) * 7 + n % 7;
    int h = hp + 3; if (h >= HH) h -= HH;
    int w = wp + 3; if (w >= HH) w -= HH;
    return (long)b * HWSZ + h * HH + w;
}

// ---------- GEMM 1: QKV = Yw @ qkv_w + qkv_b  (bf16 out, windowed rows) ----------
__global__ __launch_bounds__(256, 4) void gemm_qkv_kernel(const u16* __restrict__ A, const u16* __restrict__ Bt,
                                                          const float* __restrict__ bias, u16* __restrict__ C) {
    __shared__ u16 sA[2 * 4096], sB[2 * 4096];
    f4 acc[4][4];
    int y, x;
    gemm_core<256, 6>(A, Bt, sA, sB, acc, y, x);
    const int tid = threadIdx.x, lane = tid & 63, wv = tid >> 6;
    const int wy = wv >> 1, wx = wv & 1, qd = lane >> 4, lr = lane & 15;
    const long row0 = (long)y * 128 + wy * 64 + qd * 4;
    const int col0 = x * 128 + wx * 64 + lr;
#pragma unroll
    for (int mt = 0; mt < 4; ++mt) {
        long rb = row0 + mt * 16;
#pragma unroll
        for (int nt = 0; nt < 4; ++nt) {
            int c = col0 + nt * 16;
            float bv = bias[c];
#pragma unroll
            for (int r = 0; r < 4; ++r) C[(rb + r) * QKVW + c] = f2b(acc[mt][nt][r] + bv);
        }
    }
}

// ---------- GEMM 2: x1 += unwindow(Ow @ proj_w + proj_b) ----------
__global__ __launch_bounds__(256, 4) void gemm_proj_kernel(const u16* __restrict__ A, const u16* __restrict__ Bt,
                                                           const float* __restrict__ bias, float* __restrict__ x1) {
    __shared__ u16 sA[2 * 4096], sB[2 * 4096];
    f4 acc[4][4];
    int y, x;
    gemm_core<256, 2>(A, Bt, sA, sB, acc, y, x);
    const int tid = threadIdx.x, lane = tid & 63, wv = tid >> 6;
    const int wy = wv >> 1, wx = wv & 1, qd = lane >> 4, lr = lane & 15;
    const int row0 = y * 128 + wy * 64 + qd * 4;
    const int col0 = x * 128 + wx * 64 + lr;
#pragma unroll
    for (int mt = 0; mt < 4; ++mt) {
        long tk[4];
#pragma unroll
        for (int r = 0; r < 4; ++r) tk[r] = wtok(row0 + mt * 16 + r);
#pragma unroll
        for (int nt = 0; nt < 4; ++nt) {
            int c = col0 + nt * 16;
            float bv = bias[c];
#pragma unroll
            for (int r = 0; r < 4; ++r) x1[tk[r] * CH + c] += acc[mt][nt][r] + bv;
        }
    }
}

// ---------- GEMM 3: Hid = gelu(L2 @ w1 + b1) (bf16 out) ----------
__global__ __launch_bounds__(256, 4) void gemm_mlp1_kernel(const u16* __restrict__ A, const u16* __restrict__ Bt,
                                                           const float* __restrict__ bias, u16* __restrict__ C) {
    __shared__ u16 sA[2 * 4096], sB[2 * 4096];
    f4 acc[4][4];
    int y, x;
    gemm_core<256, 8>(A, Bt, sA, sB, acc, y, x);
    const int tid = threadIdx.x, lane = tid & 63, wv = tid >> 6;
    const int wy = wv >> 1, wx = wv & 1, qd = lane >> 4, lr = lane & 15;
    const long row0 = (long)y * 128 + wy * 64 + qd * 4;
    const int col0 = x * 128 + wx * 64 + lr;
#pragma unroll
    for (int mt = 0; mt < 4; ++mt) {
        long rb = row0 + mt * 16;
#pragma unroll
        for (int nt = 0; nt < 4; ++nt) {
            int c = col0 + nt * 16;
            float bv = bias[c];
#pragma unroll
            for (int r = 0; r < 4; ++r)
                C[(rb + r) * 1024 + c] = f2b(fgelu(acc[mt][nt][r] + bv));
        }
    }
}

// ---------- GEMM 4: out(B,C,H,W) = transpose(x1 + Hid @ w2 + b2) ----------
__global__ __launch_bounds__(256, 4) void gemm_mlp2_kernel(const u16* __restrict__ A, const u16* __restrict__ Bt,
                                                           const float* __restrict__ bias, const float* __restrict__ x1,
                                                           float* __restrict__ out) {
    __shared__ u16 sA[2 * 4096], sB[2 * 4096];
    f4 acc[4][4];
    int y, x;
    gemm_core<1024, 2>(A, Bt, sA, sB, acc, y, x);
    const int tid = threadIdx.x, lane = tid & 63, wv = tid >> 6;
    const int wy = wv >> 1, wx = wv & 1, qd = lane >> 4, lr = lane & 15;
    const long row0 = (long)y * 128 + wy * 64 + qd * 4;
    const int col0 = x * 128 + wx * 64 + lr;
#pragma unroll
    for (int mt = 0; mt < 4; ++mt) {
        long r0 = row0 + mt * 16;                 // token index, multiple of 4
        long b = r0 / HWSZ, hw = r0 - b * HWSZ;   // 3136%4==0 -> quad never crosses b
#pragma unroll
        for (int nt = 0; nt < 4; ++nt) {
            int c = col0 + nt * 16;
            float bv = bias[c];
            f4 o;
#pragma unroll
            for (int r = 0; r < 4; ++r) o[r] = acc[mt][nt][r] + bv + x1[(r0 + r) * CH + c];
            *(f4*)(out + (b * CH + c) * HWSZ + hw) = o;
        }
    }
}

// ---------- LN1 + roll(-3) + window partition; also writes f32 shortcut into x1 ----------
__global__ __launch_bounds__(256) void ln1_kernel(const float* __restrict__ x, const float* __restrict__ g,
                                                  const float* __restrict__ be, float* __restrict__ x1,
                                                  u16* __restrict__ Yw) {
    __shared__ float tile[32 * 257];
    __shared__ float red0[256], red1[256];
    __shared__ float smu[32], srs[32];
    const int tid = threadIdx.x;
    const int blk = blockIdx.x;
    const int b = blk / 98, hw0 = (blk - b * 98) * 32;
    const int ty = tid >> 5, tx = tid & 31;
    const float* xb = x + (size_t)b * (CH * HWSZ) + hw0 + tx;
    float s = 0.f, q = 0.f;
#pragma unroll
    for (int ci = 0; ci < 32; ++ci) {
        int c = ty + ci * 8;
        float v = xb[c * HWSZ];
        tile[tx * 257 + c] = v;
        s += v; q += v * v;
    }
    red0[tid] = s;
    red1[tid] = q;
    __syncthreads();
    if (tid < 32) {
        float ss = 0.f, qq = 0.f;
#pragma unroll
        for (int j = 0; j < 8; ++j) { ss += red0[j * 32 + tid]; qq += red1[j * 32 + tid]; }
        float mu = ss * (1.f / 256.f);
        float var = qq * (1.f / 256.f) - mu * mu;
        smu[tid] = mu;
        srs[tid] = rsqrtf(var + 1e-5f);
    }
    __syncthreads();
    const int cl = tid & 31, tg = tid >> 5;
#pragma unroll
    for (int it = 0; it < 4; ++it) {
        int tok = tg + it * 8;
        float mu = smu[tok], rs = srs[tok];
        int hw = hw0 + tok;
        int h = hw / HH, w = hw - h * HH;
        int hp = h - 3; if (hp < 0) hp += HH;
        int wp = w - 3; if (wp < 0) wp += HH;
        long t = (long)b * HWSZ + hw;
        long rowY = (((long)(b * 64 + (hp / 7) * 8 + wp / 7)) * 49 + (hp % 7) * 7 + (wp % 7)) * CH;
        float* xr = x1 + t * CH;
#pragma unroll
        for (int j = 0; j < 8; ++j) {
            int c = j * 32 + cl;
            float v = tile[tok * 257 + c];
            xr[c] = v;  // shortcut (pre-LN), token-major
            Yw[rowY + c] = f2b((v - mu) * rs * g[c] + be[c]);
        }
    }
}

// ---------- LN2: x1 (f32 token-major) -> bf16 ----------
__global__ __launch_bounds__(256) void ln2_kernel(const float* __restrict__ x1, const float* __restrict__ g,
                                                  const float* __restrict__ be, u16* __restrict__ L2) {
    const long t = (long)blockIdx.x * 4 + (threadIdx.x >> 6);
    const int lane = threadIdx.x & 63;
    const float4 v = *(const float4*)(x1 + t * CH + lane * 4);
    float s = v.x + v.y + v.z + v.w;
    float q = v.x * v.x + v.y * v.y + v.z * v.z + v.w * v.w;
#pragma unroll
    for (int m = 1; m < 64; m <<= 1) {
        s += __shfl_xor(s, m, 64);
        q += __shfl_xor(q, m, 64);
    }
    float mu = s * (1.f / 256.f);
    float rs = rsqrtf(q * (1.f / 256.f) - mu * mu + 1e-5f);
    const float4 gg = *(const float4*)(g + lane * 4);
    const float4 bb = *(const float4*)(be + lane * 4);
    ushort4 o;
    o.x = f2b((v.x - mu) * rs * gg.x + bb.x);
    o.y = f2b((v.y - mu) * rs * gg.y + bb.y);
    o.z = f2b((v.z - mu) * rs * gg.z + bb.z);
    o.w = f2b((v.w - mu) * rs * gg.w + bb.w);
    *(ushort4*)(L2 + t * CH + lane * 4) = o;
}

// ---------- MFMA attention: 1 wave per (window, head), 49 tokens padded to 64 ----------
__global__ __launch_bounds__(256) void attn_kernel(const u16* __restrict__ QKV, u16* __restrict__ Ow) {
    __shared__ __align__(16) u16 pbuf[4][64 * 72];  // per-wave P slab (9216 B)
    const int tid = threadIdx.x;
    const int lane = tid & 63, wv = tid >> 6;
    const int pair = blockIdx.x * 4 + wv;
    const int win = pair >> 3, hd = pair & 7;
    const int lr = lane & 15, qd = lane >> 4;
    const u16* base = QKV + (size_t)win * (49 * QKVW) + hd * 32;

    // --- S = Q K^T ---
    bf8 aq[4], bk[4];
#pragma unroll
    for (int t = 0; t < 4; ++t) {
        int rq = t * 16 + lr; if (rq > 48) rq = 48;           // clamp pad rows
        const u16* rp = base + (size_t)rq * QKVW + qd * 8;
        aq[t] = *(const bf8*)(rp);                            // Q
        bk[t] = *(const bf8*)(rp + 256);                      // K
    }
    f4 s[4][4];
#pragma unroll
    for (int mt = 0; mt < 4; ++mt)
#pragma unroll
        for (int nt = 0; nt < 4; ++nt) {
#pragma unroll
            for (int r = 0; r < 4; ++r) s[mt][nt][r] = 0.f;
            s[mt][nt] = __builtin_amdgcn_mfma_f32_16x16x32_bf16(aq[mt], bk[nt], s[mt][nt], 0, 0, 0);
        }

    // --- softmax over cols (0..48 valid), P -> LDS ---
    const float SC = 0.17677669529663687f;  // 1/sqrt(32)
    float inv[4][4];
    u16* slab = pbuf[wv];
#pragma unroll
    for (int mt = 0; mt < 4; ++mt)
#pragma unroll
        for (int r = 0; r < 4; ++r) {
            float v0 = s[mt][0][r] * SC;
            float v1 = s[mt][1][r] * SC;
            float v2 = s[mt][2][r] * SC;
            float v3 = (lr == 0) ? s[mt][3][r] * SC : -3e38f;  // col 48+lr >= 49 masked
            float mx = fmaxf(fmaxf(v0, v1), fmaxf(v2, v3));
#pragma unroll
            for (int m = 1; m < 16; m <<= 1) mx = fmaxf(mx, __shfl_xor(mx, m, 64));
            v0 = __expf(v0 - mx); v1 = __expf(v1 - mx);
            v2 = __expf(v2 - mx); v3 = __expf(v3 - mx);
            float den = (v0 + v1) + (v2 + v3);
#pragma unroll
            for (int m = 1; m < 16; m <<= 1) den += __shfl_xor(den, m, 64);
            inv[mt][r] = 1.f / den;
            u16* pr = slab + (mt * 16 + qd * 4 + r) * 72 + lr;
            pr[0] = f2b(v0); pr[16] = f2b(v1); pr[32] = f2b(v2); pr[48] = f2b(v3);
        }
    // no __syncthreads(): each wave reads only its own pbuf[wv] slab;
    // compiler lgkmcnt ordering covers ds_write -> ds_read within a wave.

    // --- O = P V ---
    f4 o[4][2];
#pragma unroll
    for (int mt = 0; mt < 4; ++mt)
#pragma unroll
        for (int nt = 0; nt < 2; ++nt)
#pragma unroll
            for (int r = 0; r < 4; ++r) o[mt][nt][r] = 0.f;
#pragma unroll
    for (int kt = 0; kt < 2; ++kt) {
        bf8 ap[4];
#pragma unroll
        for (int mt = 0; mt < 4; ++mt)
            ap[mt] = *(const bf8*)(slab + (mt * 16 + lr) * 72 + kt * 32 + qd * 8);
        bf8 bvv[2];
#pragma unroll
        for (int nt = 0; nt < 2; ++nt)
#pragma unroll
            for (int j = 0; j < 8; ++j) {
                int row = kt * 32 + qd * 8 + j; if (row > 48) row = 48;  // P=0 there anyway
                bvv[nt][j] = __builtin_bit_cast(__bf16, base[(size_t)row * QKVW + 512 + nt * 16 + lr]);
            }
#pragma unroll
        for (int mt = 0; mt < 4; ++mt)
#pragma unroll
            for (int nt = 0; nt < 2; ++nt)
                o[mt][nt] = __builtin_amdgcn_mfma_f32_16x16x32_bf16(ap[mt], bvv[nt], o[mt][nt], 0, 0, 0);
    }

    // --- store O (rows < 49) ---
#pragma unroll
    for (int mt = 0; mt < 4; ++mt)
#pragma unroll
        for (int r = 0; r < 4; ++r) {
            int row = mt * 16 + qd * 4 + r;
            if (row < 49) {
                u16* orow = Ow + ((size_t)win * 49 + row) * CH + hd * 32 + lr;
                orow[0]  = f2b(o[mt][0][r] * inv[mt][r]);
                orow[16] = f2b(o[mt][1][r] * inv[mt][r]);
            }
        }
}

// ---------- weight transpose: src[K][N] f32 -> dst[N][K] bf16, LDS 32x33 tile ----------
__global__ __launch_bounds__(256) void transp_kernel(const float* __restrict__ src, u16* __restrict__ dst,
                                                     int K, int N) {
    __shared__ float t[32][33];
    const int n0 = blockIdx.x * 32, k0 = blockIdx.y * 32;
    const int tx = threadIdx.x & 31, ty = threadIdx.x >> 5;
#pragma unroll
    for (int j = 0; j < 32; j += 8)
        t[ty + j][tx] = src[(size_t)(k0 + ty + j) * N + n0 + tx];
    __syncthreads();
#pragma unroll
    for (int j = 0; j < 32; j += 8)
        dst[(size_t)(n0 + ty + j) * K + k0 + tx] = f2b(t[tx][ty + j]);
}

extern "C" void kernel_launch(void* const* d_in, const int* in_sizes, int n_in,
                              void* d_out, int out_size, void* d_ws, size_t ws_size,
                              hipStream_t stream) {
    (void)in_sizes; (void)n_in; (void)out_size; (void)ws_size;
    const float* x      = (const float*)d_in[0];
    const float* n1_g   = (const float*)d_in[1];
    const float* n1_b   = (const float*)d_in[2];
    const float* qkv_w  = (const float*)d_in[3];
    const float* qkv_b  = (const float*)d_in[4];
    const float* proj_w = (const float*)d_in[5];
    const float* proj_b = (const float*)d_in[6];
    const float* n2_g   = (const float*)d_in[7];
    const float* n2_b   = (const float*)d_in[8];
    const float* mlp_w1 = (const float*)d_in[9];
    const float* mlp_b1 = (const float*)d_in[10];
    const float* mlp_w2 = (const float*)d_in[11];
    const float* mlp_b2 = (const float*)d_in[12];
    float* out = (float*)d_out;

    // ws carve. bufA multiplexes Yw -> Ow -> LN2out; bufB multiplexes QKV -> Hid.
    uint8_t* w = (uint8_t*)d_ws;
    u16* bufA = (u16*)(w);                                     //  51,380,224
    u16* bufB = (u16*)(w + 51380224);                          // 205,520,896
    float* x1 = (float*)(w + 51380224 + 205520896);            // 102,760,448
    u16* wq  = (u16*)(w + 359661568);
    u16* wp  = (u16*)(w + 360054784);
    u16* w1t = (u16*)(w + 360185856);
    u16* w2t = (u16*)(w + 360710144);

    transp_kernel<<<dim3(24, 8),  256, 0, stream>>>(qkv_w,  wq,  256, 768);
    transp_kernel<<<dim3(8, 8),   256, 0, stream>>>(proj_w, wp,  256, 256);
    transp_kernel<<<dim3(32, 8),  256, 0, stream>>>(mlp_w1, w1t, 256, 1024);
    transp_kernel<<<dim3(8, 32),  256, 0, stream>>>(mlp_w2, w2t, 1024, 256);
    ln1_kernel<<<3136, 256, 0, stream>>>(x, n1_g, n1_b, x1, bufA);
    gemm_qkv_kernel<<<6 * 784, 256, 0, stream>>>(bufA, wq, qkv_b, bufB);
    attn_kernel<<<4096, 256, 0, stream>>>(bufB, bufA);
    gemm_proj_kernel<<<2 * 784, 256, 0, stream>>>(bufA, wp, proj_b, x1);
    ln2_kernel<<<25088, 256, 0, stream>>>(x1, n2_g, n2_b, bufA);
    gemm_mlp1_kernel<<<8 * 784, 256, 0, stream>>>(bufA, w1t, mlp_b1, bufB);
    gemm_mlp2_kernel<<<2 * 784, 256, 0, stream>>>(bufB, w2t, mlp_b2, x1, out);
}